// Round 1
// 1887.800 us; speedup vs baseline: 1.1636x; 1.1636x over previous
//
#include <hip/hip_runtime.h>
#include <cmath>

#define BB 128
#define TT 256
#define DD 512
#define HH 256
#define G3 768   // 3*H

typedef float v2f __attribute__((ext_vector_type(2)));
// packed fp32 FMA (CDNA2+; this is how the 157.3 TF fp32 vector peak is reached)
#define PKFMA(acc, a, b) asm("v_pk_fma_f32 %0, %1, %2, %0" : "+v"(acc) : "v"(a), "v"(b))

// ---- GEMM: C[m,n] = bias[n] + sum_k A[m,k]*W[n,k]; A (M,K), W (N,K) ------
__global__ __launch_bounds__(256) void gemm_abt(
    const float* __restrict__ A, const float* __restrict__ W,
    const float* __restrict__ bias, float* __restrict__ C,
    int M, int N, int K)
{
  __shared__ float sA[16][132];
  __shared__ float sB[16][132];
  const int tid = threadIdx.x;
  const int row0 = blockIdx.y * 128, col0 = blockIdx.x * 128;
  const int tx = tid & 15, ty = tid >> 4;
  float acc[8][8];
#pragma unroll
  for (int i = 0; i < 8; i++)
#pragma unroll
    for (int j = 0; j < 8; j++) acc[i][j] = 0.f;

  for (int k0 = 0; k0 < K; k0 += 16) {
    __syncthreads();
#pragma unroll
    for (int i = 0; i < 2; i++) {
      int q = tid + i * 256;
      int r = q >> 2, k4 = (q & 3) * 4;
      float4 av = *(const float4*)(A + (size_t)(row0 + r) * K + k0 + k4);
      sA[k4 + 0][r] = av.x; sA[k4 + 1][r] = av.y;
      sA[k4 + 2][r] = av.z; sA[k4 + 3][r] = av.w;
      float4 wv = make_float4(0.f, 0.f, 0.f, 0.f);
      if (col0 + r < N) wv = *(const float4*)(W + (size_t)(col0 + r) * K + k0 + k4);
      sB[k4 + 0][r] = wv.x; sB[k4 + 1][r] = wv.y;
      sB[k4 + 2][r] = wv.z; sB[k4 + 3][r] = wv.w;
    }
    __syncthreads();
#pragma unroll
    for (int k = 0; k < 16; k++) {
      float a0[8], b0[8];
      *(float4*)&a0[0] = *(const float4*)&sA[k][ty * 4];
      *(float4*)&a0[4] = *(const float4*)&sA[k][64 + ty * 4];
      *(float4*)&b0[0] = *(const float4*)&sB[k][tx * 4];
      *(float4*)&b0[4] = *(const float4*)&sB[k][64 + tx * 4];
#pragma unroll
      for (int i = 0; i < 8; i++)
#pragma unroll
        for (int j = 0; j < 8; j++) acc[i][j] += a0[i] * b0[j];
    }
  }
#pragma unroll
  for (int i = 0; i < 8; i++) {
    int r = row0 + ((i < 4) ? (ty * 4 + i) : (64 + ty * 4 + i - 4));
#pragma unroll
    for (int jq = 0; jq < 2; jq++) {
      int c = col0 + jq * 64 + tx * 4;
      if (c < N) {
        float4 v;
        v.x = acc[i][jq * 4 + 0] + bias[c + 0];
        v.y = acc[i][jq * 4 + 1] + bias[c + 1];
        v.z = acc[i][jq * 4 + 2] + bias[c + 2];
        v.w = acc[i][jq * 4 + 3] + bias[c + 3];
        *(float4*)(C + (size_t)r * N + c) = v;
      }
    }
  }
}

// ---- LPT schedule: order_b[rank] = batch, ranked by length descending ----
__global__ void sched_kernel(const int* __restrict__ lengths,
                             int* __restrict__ order_b)
{
  const int b = threadIdx.x;
  if (b < BB) {
    const int L = lengths[b];
    int rank = 0;
    for (int j = 0; j < BB; j++) {
      const int Lj = lengths[j];
      rank += (Lj > L) || (Lj == L && j < b);
    }
    order_b[rank] = b;
  }
}

// ---- persistent register-stationary GRU with LPT work queue -------------
// 256 persistent blocks (1/CU, all co-resident). Tickets claimed from an
// atomic counter in length-descending order (LPT): ticket tk -> pair
// q=tk>>1, half=tk&1; fused: batch=order_b[q>>1], dir=q&1. The two halves
// of a pair are consecutive tickets, so they are claimed by the first two
// free workers and run concurrently (deadlock-free: every ticket < ntick
// is claimed exactly once by a worker != the partner's claimer).
// Per step (thread ul=tid>>1, kc=tid&1, unit u=half*128+ul):
//   phase A: FMA over OWN-half k-slice [half*128+kc*64, +64)  (h local)
//   poll partner h_{t-1} (parity-double-buffered tagged slot; race-free:
//     our tag t+1 store happens only after our tag-t reads, so partner
//     can overwrite buf[t&1] (tag t+2) only after we consumed tag t)
//   phase B: FMA over PARTNER-half k-slice, then shfl-reduce + activations.
// Weights pinned in VGPR/AGPR (2*48 float4/thread); depth-8 rotating LDS
// buffer covers ds_read_b128 latency; v_pk_fma_f32 halves FMA issue.
__global__ __launch_bounds__(256, 1) void gru_pair_kernel(
    const float* __restrict__ xg_f, const float* __restrict__ xg_b,
    const float* __restrict__ whh_f, const float* __restrict__ whh_b,
    const float* __restrict__ bhh_f, const float* __restrict__ bhh_b,
    const int* __restrict__ lengths, float* __restrict__ outp,
    unsigned long long* __restrict__ Hx,   // [2][BB][2 parity][HH] tagged
    const int* __restrict__ order_b,       // [BB] desc-length batch order
    int* __restrict__ ctr,                 // [2] ticket counters (zeroed)
    int dir_arg, int ntick)                // -1: fused (both dirs)
{
  const int tid = threadIdx.x;
  __shared__ float h_s[HH];
  __shared__ int s_tk;

  for (;;) {
    if (tid == 0) s_tk = atomicAdd(ctr + (dir_arg >= 0 ? dir_arg : 0), 1);
    __syncthreads();
    const int tk = s_tk;
    __syncthreads();
    if (tk >= ntick) return;

    int batch, dir;
    const int half = tk & 1;
    if (dir_arg < 0) { const int q = tk >> 1; batch = order_b[q >> 1]; dir = q & 1; }
    else             { const int q = tk >> 1; batch = order_b[q];      dir = dir_arg; }

    const int ul = tid >> 1, kc = tid & 1;
    const int u  = half * 128 + ul;
    const int po = (1 - half) * 128;
    const int koA = half * 128 + kc * 64;        // own-half k slice
    const int koB = (1 - half) * 128 + kc * 64;  // partner-half k slice
    const int len = lengths[batch];
    const float* xg   = dir ? xg_b  : xg_f;
    const float* w_hh = dir ? whh_b : whh_f;
    const float* bhh  = dir ? bhh_b : bhh_f;
    unsigned long long* slotbase = Hx + (size_t)(dir * BB + batch) * (2 * HH);

    if (tid < HH) h_s[tid] = 0.f;

    // one-time (per task) weight load; asm barriers pin values in registers
    float4 wrA[16], wzA[16], wnA[16], wrB[16], wzB[16], wnB[16];
    {
      const float* pr = w_hh + (size_t)u * HH;
      const float* pz = pr + (size_t)HH * HH;
      const float* pn = pr + (size_t)2 * HH * HH;
#pragma unroll
      for (int i = 0; i < 16; i++) {
        wrA[i] = *(const float4*)(pr + koA + 4 * i);
        wzA[i] = *(const float4*)(pz + koA + 4 * i);
        wnA[i] = *(const float4*)(pn + koA + 4 * i);
        wrB[i] = *(const float4*)(pr + koB + 4 * i);
        wzB[i] = *(const float4*)(pz + koB + 4 * i);
        wnB[i] = *(const float4*)(pn + koB + 4 * i);
      }
#pragma unroll
      for (int i = 0; i < 16; i++) {
        asm volatile("" : "+v"(wrA[i].x), "+v"(wrA[i].y), "+v"(wrA[i].z), "+v"(wrA[i].w));
        asm volatile("" : "+v"(wzA[i].x), "+v"(wzA[i].y), "+v"(wzA[i].z), "+v"(wzA[i].w));
        asm volatile("" : "+v"(wnA[i].x), "+v"(wnA[i].y), "+v"(wnA[i].z), "+v"(wnA[i].w));
        asm volatile("" : "+v"(wrB[i].x), "+v"(wrB[i].y), "+v"(wrB[i].z), "+v"(wrB[i].w));
        asm volatile("" : "+v"(wzB[i].x), "+v"(wzB[i].y), "+v"(wzB[i].z), "+v"(wzB[i].w));
        asm volatile("" : "+v"(wnB[i].x), "+v"(wnB[i].y), "+v"(wnB[i].z), "+v"(wnB[i].w));
      }
    }
    const float br = bhh[u], bz = bhh[HH + u], bn = bhh[2 * HH + u];
    __syncthreads();

#define GATE_PHASE(KO, WR, WZ, WN)                                           \
    {                                                                        \
      const float* hp = h_s + (KO);                                          \
      float4 hb[8];                                                          \
      _Pragma("unroll")                                                      \
      for (int i2 = 0; i2 < 8; i2++) hb[i2] = *(const float4*)(hp + 4 * i2); \
      _Pragma("unroll")                                                      \
      for (int i2 = 0; i2 < 16; i2++) {                                      \
        float4 h4 = hb[i2 & 7];                                              \
        if (i2 < 8) hb[i2] = *(const float4*)(hp + 4 * (8 + i2));            \
        const v2f* h2  = (const v2f*)&h4;                                    \
        const v2f* w2r = (const v2f*)&WR[i2];                                \
        const v2f* w2z = (const v2f*)&WZ[i2];                                \
        const v2f* w2n = (const v2f*)&WN[i2];                                \
        PKFMA(ar2, h2[0], w2r[0]); PKFMA(ar2, h2[1], w2r[1]);                \
        PKFMA(az2, h2[0], w2z[0]); PKFMA(az2, h2[1], w2z[1]);                \
        PKFMA(an2, h2[0], w2n[0]); PKFMA(an2, h2[1], w2n[1]);                \
      }                                                                      \
    }

    // xg prefetch for t=0 (only kc==0 lanes consume it)
    int p = dir ? (len - 1) : 0;
    float xr_c = 0.f, xz_c = 0.f, xn_c = 0.f;
    if (kc == 0) {
      const float* x0 = xg + ((size_t)batch * TT + p) * G3;
      xr_c = x0[u]; xz_c = x0[HH + u]; xn_c = x0[2 * HH + u];
    }

    for (int t = 0; t < len; t++) {
      // prefetch next step's xg (hidden under the FMA phases)
      float xr_n = 0.f, xz_n = 0.f, xn_n = 0.f;
      if (kc == 0 && t + 1 < len) {
        const int pnx = dir ? (len - 2 - t) : (t + 1);
        const float* xp = xg + ((size_t)batch * TT + pnx) * G3;
        xr_n = xp[u]; xz_n = xp[HH + u]; xn_n = xp[2 * HH + u];
      }
      const float hold = h_s[u];
      v2f ar2 = {0.f, 0.f}, az2 = {0.f, 0.f}, an2 = {0.f, 0.f};

      // phase A: own-half k-slice (h available locally; partner h in flight)
      GATE_PHASE(koA, wrA, wzA, wnA);

      // poll partner h_{t-1} into LDS (parity buffer t&1, tag t)
      if (t > 0 && tid < 128) {
        const unsigned wtag = (unsigned)t;
        unsigned long long* sp = slotbase + (size_t)(t & 1) * HH + po + tid;
        unsigned long long v;
        do {
          v = __hip_atomic_load(sp, __ATOMIC_RELAXED, __HIP_MEMORY_SCOPE_AGENT);
        } while ((unsigned)(v >> 32) != wtag);
        h_s[po + tid] = __uint_as_float((unsigned)v);
      }
      __syncthreads();

      // phase B: partner-half k-slice
      GATE_PHASE(koB, wrB, wzB, wnB);

      float ar = ar2.x + ar2.y, az = az2.x + az2.y, an = an2.x + an2.y;
      ar += __shfl_xor(ar, 1);
      az += __shfl_xor(az, 1);
      an += __shfl_xor(an, 1);

      if (kc == 0) {
        float r = 1.f / (1.f + expf(-(xr_c + ar + br)));
        float z = 1.f / (1.f + expf(-(xz_c + az + bz)));
        float n = tanhf(xn_c + r * (an + bn));
        float hn = (1.f - z) * n + z * hold;
        h_s[u] = hn;
        unsigned long long pk2 =
            ((unsigned long long)(unsigned)(t + 1) << 32) |
            (unsigned long long)__float_as_uint(hn);
        __hip_atomic_store(slotbase + (size_t)((t + 1) & 1) * HH + u, pk2,
                           __ATOMIC_RELAXED, __HIP_MEMORY_SCOPE_AGENT);
        outp[((size_t)batch * TT + p) * (2 * HH) + dir * HH + u] = hn;
      }
      __syncthreads();
      xr_c = xr_n; xz_c = xz_n; xn_c = xn_n;
      p += dir ? -1 : 1;
    }
#undef GATE_PHASE
  }
}

// ------------- scores from hmid: relu, dot w2, +b2; mask t>=len ----------
__global__ __launch_bounds__(256) void score2_kernel(
    const float* __restrict__ hmid, const float* __restrict__ w2,
    const float* __restrict__ b2, const int* __restrict__ lengths,
    float* __restrict__ scores)
{
  const int wv = threadIdx.x >> 6, lane = threadIdx.x & 63;
  const int bt = blockIdx.x * 4 + wv;
  const int b = bt >> 8, t = bt & 255;
  float v = 0.f;
  if (t < lengths[b]) {
    float hv = fmaxf(hmid[(size_t)bt * 64 + lane], 0.f);
    v = hv * w2[lane];
#pragma unroll
    for (int o = 32; o > 0; o >>= 1) v += __shfl_down(v, o);
    v += b2[0];
  }
  if (lane == 0) scores[bt] = v;
}

// -------- softmax + top-3 + normalize + seq_feat, 1 block per batch ------
__global__ __launch_bounds__(256) void attn_kernel(
    const float* __restrict__ scores, const float* __restrict__ outp,
    const float* __restrict__ temp_ptr, const int* __restrict__ lengths,
    float* __restrict__ seq_feat)
{
  const int b = blockIdx.x;
  const int t = threadIdx.x;
  const int len = lengths[b];
  float temp = fminf(fmaxf(temp_ptr[0], 0.001f), 10.0f);
  __shared__ float red[256];
  __shared__ int redi[256];
  __shared__ float topv[3]; __shared__ int topi[3];
  __shared__ float vn[3]; __shared__ float vsum_s;
  const bool valid = t < len;
  float logit = valid ? scores[b * TT + t] / temp : -INFINITY;
  red[t] = logit; __syncthreads();
  for (int s = 128; s > 0; s >>= 1) {
    if (t < s) red[t] = fmaxf(red[t], red[t + s]);
    __syncthreads();
  }
  float mx = red[0]; __syncthreads();
  float e = valid ? expf(logit - mx) : 0.f;
  red[t] = e; __syncthreads();
  for (int s = 128; s > 0; s >>= 1) {
    if (t < s) red[t] += red[t + s];
    __syncthreads();
  }
  float sum = red[0]; __syncthreads();
  float myp = e / sum;
  for (int it = 0; it < 3; it++) {
    red[t] = myp; redi[t] = t; __syncthreads();
    for (int s = 128; s > 0; s >>= 1) {
      if (t < s) {
        float v2 = red[t + s]; int i2 = redi[t + s];
        if (v2 > red[t] || (v2 == red[t] && i2 < redi[t])) { red[t] = v2; redi[t] = i2; }
      }
      __syncthreads();
    }
    if (t == 0) { topv[it] = red[0]; topi[it] = redi[0]; }
    __syncthreads();
    if (t == topi[it]) myp = -1.f;
    __syncthreads();
  }
  if (t == 0) {
    int k_act = len < 3 ? len : 3;
    float vsum = 0.f;
    for (int jj = 0; jj < 3; jj++) if (jj < k_act) vsum += topv[jj];
    vsum_s = vsum;
    float denom = fmaxf(vsum, 1e-8f);
    for (int jj = 0; jj < 3; jj++) vn[jj] = (jj < k_act) ? topv[jj] / denom : 0.f;
  }
  __syncthreads();
  if (vsum_s > 1e-8f) {
    for (int hh = t; hh < 2 * HH; hh += 256) {
      float s = 0.f;
      for (int jj = 0; jj < 3; jj++)
        s += vn[jj] * outp[((size_t)b * TT + topi[jj]) * (2 * HH) + hh];
      seq_feat[b * 2 * HH + hh] = s;
    }
  } else {
    float inv = 1.f / ((float)len + 1e-8f);
    for (int hh = t; hh < 2 * HH; hh += 256) {
      float s = 0.f;
      for (int tt2 = 0; tt2 < len; tt2++)
        s += outp[((size_t)b * TT + tt2) * (2 * HH) + hh];
      seq_feat[b * 2 * HH + hh] = s * inv;
    }
  }
}

// ------------------- final heads: (B,11) then (B,10) ---------------------
__global__ __launch_bounds__(256) void head_kernel(
    const float* __restrict__ seq_feat,
    const float* __restrict__ w_tens, const float* __restrict__ b_tens,
    const float* __restrict__ w_ones, const float* __restrict__ b_ones,
    float* __restrict__ d_out)
{
  const int b = blockIdx.x;
  const int lane = threadIdx.x & 63, wv = threadIdx.x >> 6;
  const float* sf = seq_feat + (size_t)b * 2 * HH;
  for (int o = wv; o < 21; o += 4) {
    const float* wr = (o < 11) ? (w_tens + (size_t)o * 2 * HH)
                               : (w_ones + (size_t)(o - 11) * 2 * HH);
    float s = 0.f;
    for (int e2 = lane; e2 < 2 * HH; e2 += 64) s += sf[e2] * wr[e2];
#pragma unroll
    for (int off2 = 32; off2 > 0; off2 >>= 1) s += __shfl_down(s, off2);
    if (lane == 0) {
      if (o < 11) d_out[b * 11 + o] = s + b_tens[o];
      else d_out[BB * 11 + b * 10 + (o - 11)] = s + b_ones[o - 11];
    }
  }
}

extern "C" void kernel_launch(void* const* d_in, const int* in_sizes, int n_in,
                              void* d_out, int out_size, void* d_ws, size_t ws_size,
                              hipStream_t stream)
{
  const float* feats       = (const float*)d_in[0];
  const int*   lengths     = (const int*)d_in[1];
  const float* temperature = (const float*)d_in[2];
  const float* w_ih_f = (const float*)d_in[3];
  const float* w_hh_f = (const float*)d_in[4];
  const float* b_ih_f = (const float*)d_in[5];
  const float* b_hh_f = (const float*)d_in[6];
  const float* w_ih_b = (const float*)d_in[7];
  const float* w_hh_b = (const float*)d_in[8];
  const float* b_ih_b = (const float*)d_in[9];
  const float* b_hh_b = (const float*)d_in[10];
  const float* w1 = (const float*)d_in[11];
  const float* b1 = (const float*)d_in[12];
  const float* w2 = (const float*)d_in[13];
  const float* b2 = (const float*)d_in[14];
  const float* w_tens = (const float*)d_in[15];
  const float* b_tens = (const float*)d_in[16];
  const float* w_ones = (const float*)d_in[17];
  const float* b_ones = (const float*)d_in[18];
  float* out = (float*)d_out;

  const size_t xg_sz   = (size_t)BB * TT * G3 * 4;        // 100.7 MB
  const size_t outp_sz = (size_t)BB * TT * 2 * HH * 4;    // 67.1 MB
  const size_t hx_sz   = (size_t)2 * BB * 2 * HH * 8;     // 1 MiB (parity-dbuf)
  const size_t sch_sz  = 1024;                            // order_b[128] + ctr[2]
  const size_t fused_need = 2 * xg_sz + outp_sz + hx_sz + sch_sz;
  char* ws = (char*)d_ws;

  if (ws_size >= fused_need) {
    // ---------- fused path: both xg buffers live, one 256-worker GRU -----
    float* xg_f = (float*)ws;
    float* xg_b = (float*)(ws + xg_sz);
    float* outp = (float*)(ws + 2 * xg_sz);
    unsigned long long* Hx = (unsigned long long*)(ws + 2 * xg_sz + outp_sz);
    int* order_b = (int*)(ws + 2 * xg_sz + outp_sz + hx_sz);
    int* ctrp    = order_b + BB;
    float* hmid     = xg_f;                  // aliases (xg dead after GRU)
    float* scores   = xg_f + (size_t)BB * TT * 64;
    float* seq_feat = scores + (size_t)BB * TT;

    hipMemsetAsync(Hx, 0, hx_sz + sch_sz, stream);        // slots + counters
    sched_kernel<<<1, 128, 0, stream>>>(lengths, order_b);
    gemm_abt<<<dim3(6, 256), 256, 0, stream>>>(feats, w_ih_f, b_ih_f, xg_f, BB * TT, G3, DD);
    gemm_abt<<<dim3(6, 256), 256, 0, stream>>>(feats, w_ih_b, b_ih_b, xg_b, BB * TT, G3, DD);
    gru_pair_kernel<<<256, 256, 0, stream>>>(
        xg_f, xg_b, w_hh_f, w_hh_b, b_hh_f, b_hh_b, lengths, outp, Hx,
        order_b, ctrp, -1, 4 * BB);
    gemm_abt<<<dim3(1, 256), 256, 0, stream>>>(outp, w1, b1, hmid, BB * TT, 64, 2 * HH);
    score2_kernel<<<BB * TT / 4, 256, 0, stream>>>(hmid, w2, b2, lengths, scores);
    attn_kernel<<<BB, 256, 0, stream>>>(scores, outp, temperature, lengths, seq_feat);
    head_kernel<<<BB, 256, 0, stream>>>(seq_feat, w_tens, b_tens, w_ones, b_ones, out);
  } else {
    // ---------- fallback: xg shared, two serial GRU launches -------------
    float* xg   = (float*)ws;
    float* outp = (float*)(ws + xg_sz);
    unsigned long long* Hx = (unsigned long long*)(ws + xg_sz + outp_sz);
    int* order_b = (int*)(ws + xg_sz + outp_sz + hx_sz);
    int* ctrp    = order_b + BB;
    float* hmid     = xg;
    float* scores   = xg + (size_t)BB * TT * 64;
    float* seq_feat = scores + (size_t)BB * TT;

    hipMemsetAsync(Hx, 0, hx_sz + sch_sz, stream);
    sched_kernel<<<1, 128, 0, stream>>>(lengths, order_b);
    gemm_abt<<<dim3(6, 256), 256, 0, stream>>>(feats, w_ih_f, b_ih_f, xg, BB * TT, G3, DD);
    gru_pair_kernel<<<256, 256, 0, stream>>>(
        xg, xg, w_hh_f, w_hh_b, b_hh_f, b_hh_b, lengths, outp, Hx,
        order_b, ctrp, 0, 2 * BB);
    gemm_abt<<<dim3(6, 256), 256, 0, stream>>>(feats, w_ih_b, b_ih_b, xg, BB * TT, G3, DD);
    gru_pair_kernel<<<256, 256, 0, stream>>>(
        xg, xg, w_hh_f, w_hh_b, b_hh_f, b_hh_b, lengths, outp, Hx,
        order_b, ctrp, 1, 2 * BB);
    gemm_abt<<<dim3(1, 256), 256, 0, stream>>>(outp, w1, b1, hmid, BB * TT, 64, 2 * HH);
    score2_kernel<<<BB * TT / 4, 256, 0, stream>>>(hmid, w2, b2, lengths, scores);
    attn_kernel<<<BB, 256, 0, stream>>>(scores, outp, temperature, lengths, seq_feat);
    head_kernel<<<BB, 256, 0, stream>>>(seq_feat, w_tens, b_tens, w_ones, b_ones, out);
  }
}